// Round 1
// 282.899 us; speedup vs baseline: 1.0477x; 1.0477x over previous
//
#include <hip/hip_runtime.h>
#include <hip/hip_bf16.h>
#include <stdint.h>
#include <stddef.h>

// out[M,N] = X[M,K] @ sign(W[N,K])^T + bias[N];  M=N=K=4096, fp32 in/out.
#define M_DIM 4096
#define N_DIM 4096
#define K_DIM 4096
#define BM 256
#define BN 256
#define BK 64
#define NKT (K_DIM / BK)          // 64 K-tiles
#define BKB (BK * 2)              // K-tile byte stride in a row = 128 B
#define RSTRIDE ((size_t)64 * K_DIM * 2)  // 64-row staging-round stride (bytes)

typedef __bf16 bf16;
typedef __attribute__((ext_vector_type(4))) __bf16 bf16x4;
typedef __attribute__((ext_vector_type(8))) __bf16 bf16x8;
typedef __attribute__((ext_vector_type(4))) float f32x4;

// ---------------------------------------------------------------------------
// Prep: x fp32->bf16 ; w fp32->sign(w) bf16. (unchanged, verified)
// ---------------------------------------------------------------------------
__global__ __launch_bounds__(256) void prep_kernel(const float* __restrict__ x,
                                                   const float* __restrict__ w,
                                                   bf16* __restrict__ xb,
                                                   bf16* __restrict__ wb) {
    const int idx = blockIdx.x * 256 + threadIdx.x;   // 0 .. 4,194,303
    float4 xv = ((const float4*)x)[idx];
    bf16x4 xo;
    xo[0] = (bf16)xv.x; xo[1] = (bf16)xv.y; xo[2] = (bf16)xv.z; xo[3] = (bf16)xv.w;
    ((bf16x4*)xb)[idx] = xo;

    float4 wv = ((const float4*)w)[idx];
    bf16x4 wo;
    wo[0] = (bf16)((wv.x > 0.f) ? 1.f : ((wv.x < 0.f) ? -1.f : 0.f));
    wo[1] = (bf16)((wv.y > 0.f) ? 1.f : ((wv.y < 0.f) ? -1.f : 0.f));
    wo[2] = (bf16)((wv.z > 0.f) ? 1.f : ((wv.z < 0.f) ? -1.f : 0.f));
    wo[3] = (bf16)((wv.w > 0.f) ? 1.f : ((wv.w < 0.f) ? -1.f : 0.f));
    ((bf16x4*)wb)[idx] = wo;
}

// ---------------------------------------------------------------------------
// GEMM: 256x256 tile, 8 waves (2M x 4N), BK=64, 8-phase counted-vmcnt schedule
// (T2 granule swizzle + T3/T4 counted vmcnt(6) + T5 setprio).
// LDS: 2 x (A 32KB + B 32KB) = 128 KB, 1 block/CU, 2 waves/SIMD.
//
// Staging rounds (1 global_load_lds/thread each, 64 rows = 8KB):
//   a0..a3 = A rows [0,64)[64,128)[128,192)[192,256); b0..b3 same for B.
// Region last-read phases (within a K-tile; B-frags reg-cached at phase 0):
//   b0..b3: phase 0   | a0,a2: phase 1   | a1,a3: phase 3
// Issue schedule during tile t (2 issues/phase, all barrier-separated from
// the overwritten region's last read):
//   ph0: (t+1).a1,a3  -> buf^1 (last read tile t-1 ph3)
//   ph1: (t+2).b0,b1  -> buf   (last read ph0)
//   ph2: (t+2).b2,b3  -> buf   (last read ph0)
//   ph3: (t+2).a0,a2  -> buf   (last read ph1)
// Boundary: s_waitcnt vmcnt(6) keeps (t+2)'s 6 rounds in flight, guarantees
// all of tile t+1 landed. Raw s_barrier only (no compiler vmcnt(0) drain).
// ---------------------------------------------------------------------------
__device__ __forceinline__ void load_lds16(const void* g, void* l) {
    __builtin_amdgcn_global_load_lds(
        (const __attribute__((address_space(1))) void*)g,
        (__attribute__((address_space(3))) void*)l, 16, 0, 0);
}

__global__ __launch_bounds__(512, 2) void gemm_bin_kernel(const bf16* __restrict__ A,
                                                          const bf16* __restrict__ Bw,
                                                          const float* __restrict__ bias,
                                                          float* __restrict__ C) {
    // Row = 64 bf16 = 128 B = 8 granules of 16 B. Granule g of row r lives at
    // slot s = g ^ (r&7)  (bank-conflict-free, R2-verified scheme).
    __shared__ __align__(16) bf16 As[2][BM * BK];   // 2 x 32 KB
    __shared__ __align__(16) bf16 Bs[2][BM * BK];   // 2 x 32 KB

    const int tid  = threadIdx.x;
    const int lane = tid & 63;
    const int wave = tid >> 6;        // 0..7
    const int wm   = wave >> 2;       // 0..1 (M half)
    const int wn   = wave & 3;        // 0..3 (N quarter)

    const int tileM = blockIdx.y * BM;
    const int tileN = blockIdx.x * BN;

    // Staging: round r, wave stages rows r*64 + wave*8 + (lane>>3).
    // LDS dest is linear (chunk base + lane*16); source granule pre-swizzled:
    // q = (lane&7) ^ (lane>>3)  (since row&7 == lane>>3 for 8-aligned chunks).
    const int rowInC = lane >> 3;
    const int q_src  = (lane & 7) ^ rowInC;
    const char* aSrc = (const char*)A  + ((size_t)(tileM + wave * 8 + rowInC) * K_DIM + q_src * 8) * 2;
    const char* bSrc = (const char*)Bw + ((size_t)(tileN + wave * 8 + rowInC) * K_DIM + q_src * 8) * 2;

#define STAGE_A(B_, R_, KOFF_) load_lds16(aSrc + (size_t)(R_) * RSTRIDE + (KOFF_), \
                                          &As[B_][((R_) * 64 + wave * 8) * BK])
#define STAGE_B(B_, R_, KOFF_) load_lds16(bSrc + (size_t)(R_) * RSTRIDE + (KOFF_), \
                                          &Bs[B_][((R_) * 64 + wave * 8) * BK])

    f32x4 acc[8][4];
#pragma unroll
    for (int i = 0; i < 8; ++i)
#pragma unroll
        for (int j = 0; j < 4; ++j)
            acc[i][j] = (f32x4){0.f, 0.f, 0.f, 0.f};

    bf16x8 bfr[4][2];   // B-frags register-cached across a K-tile (read at phase 0)

    // Fragment reads: lane = qf*16 + l15; granule g = kk*4 + qf at row base+l15;
    // slot s = g ^ (l15&7) (row&7 == l15&7 since bases are 16-aligned).
    const int l15 = lane & 15;
    const int qf  = lane >> 4;
    const int fragRowA = wm * 128 + l15;
    const int fragRowB = wn * 64 + l15;
    const int s0 = (0 + qf) ^ (l15 & 7);   // kk=0
    const int s1 = (4 + qf) ^ (l15 & 7);   // kk=1

#define READ_A(B_, P_) \
    _Pragma("unroll") \
    for (int ii = 0; ii < 2; ++ii) { \
        af[ii][0] = *(const bf16x8*)&As[B_][(fragRowA + (2 * (P_) + ii) * 16) * BK + s0 * 8]; \
        af[ii][1] = *(const bf16x8*)&As[B_][(fragRowA + (2 * (P_) + ii) * 16) * BK + s1 * 8]; \
    }

#define READ_B(B_) \
    _Pragma("unroll") \
    for (int j = 0; j < 4; ++j) { \
        bfr[j][0] = *(const bf16x8*)&Bs[B_][(fragRowB + j * 16) * BK + s0 * 8]; \
        bfr[j][1] = *(const bf16x8*)&Bs[B_][(fragRowB + j * 16) * BK + s1 * 8]; \
    }

#define MFMA16(P_) \
    _Pragma("unroll") \
    for (int ii = 0; ii < 2; ++ii) \
        _Pragma("unroll") \
        for (int j = 0; j < 4; ++j) { \
            acc[2 * (P_) + ii][j] = __builtin_amdgcn_mfma_f32_16x16x32_bf16(af[ii][0], bfr[j][0], acc[2 * (P_) + ii][j], 0, 0, 0); \
            acc[2 * (P_) + ii][j] = __builtin_amdgcn_mfma_f32_16x16x32_bf16(af[ii][1], bfr[j][1], acc[2 * (P_) + ii][j], 0, 0, 0); \
        }

    // Phase: reads -> stage issues -> barrier -> prio MFMA cluster -> barrier.
    // sched_barrier(0) after the closing barrier pins phase boundaries so stage
    // issues can never hoist above a barrier (would break the overwrite-window
    // safety) and next-tile LDS reads can't hoist above the vmcnt wait.
#define PHASE(B_, P_, ISS0, ISS1, TAIL) do { \
        bf16x8 af[2][2]; \
        READ_A(B_, P_); \
        if ((P_) == 0) READ_B(B_); \
        ISS0; \
        ISS1; \
        __builtin_amdgcn_s_barrier(); \
        __builtin_amdgcn_s_setprio(1); \
        MFMA16(P_); \
        __builtin_amdgcn_s_setprio(0); \
        TAIL; \
        __builtin_amdgcn_s_barrier(); \
        __builtin_amdgcn_sched_barrier(0); \
    } while (0)

#define KTILE(B_, K1_, K2_) do { \
        PHASE(B_, 0, STAGE_A((B_) ^ 1, 1, K1_), STAGE_A((B_) ^ 1, 3, K1_), (void)0); \
        PHASE(B_, 1, STAGE_B(B_, 0, K2_),       STAGE_B(B_, 1, K2_),       (void)0); \
        PHASE(B_, 2, STAGE_B(B_, 2, K2_),       STAGE_B(B_, 3, K2_),       (void)0); \
        PHASE(B_, 3, STAGE_A(B_, 0, K2_),       STAGE_A(B_, 2, K2_), \
              asm volatile("s_waitcnt vmcnt(6)" ::: "memory")); \
    } while (0)

    // ---- prologue: tile0 fully (oldest 8), then tile1's {b0..b3,a0,a2} ----
    STAGE_B(0, 0, 0);   STAGE_B(0, 1, 0);   STAGE_B(0, 2, 0);   STAGE_B(0, 3, 0);
    STAGE_A(0, 0, 0);   STAGE_A(0, 2, 0);   STAGE_A(0, 1, 0);   STAGE_A(0, 3, 0);
    STAGE_B(1, 0, BKB); STAGE_B(1, 1, BKB); STAGE_B(1, 2, BKB); STAGE_B(1, 3, BKB);
    STAGE_A(1, 0, BKB); STAGE_A(1, 2, BKB);
    asm volatile("s_waitcnt vmcnt(6)" ::: "memory");   // tile0 landed; tile1 6-in-flight
    __builtin_amdgcn_s_barrier();
    __builtin_amdgcn_sched_barrier(0);

    // ---- main loop: 2 K-tiles per iteration (static buffer parity) ---------
    // Tail prefetches (tiles 64,65) wrap their K-offset to 0: the loads target
    // the buffer NOT read by the final tile -> harmless, keeps loop branch-free.
    for (int kt = 0; kt < NKT; kt += 2) {
        const int k1a = (kt + 1) * BKB;                               // tile kt+1
        const int k2a = (kt + 2 < NKT) ? (kt + 2) * BKB : 0;          // tile kt+2
        KTILE(0, k1a, k2a);
        const int k2b = (kt + 3 < NKT) ? (kt + 3) * BKB : 0;          // tile kt+3
        KTILE(1, k2a, k2b);
    }

    // ---- epilogue: C/D layout col = lane&15, row = (lane>>4)*4 + reg -------
#pragma unroll
    for (int j = 0; j < 4; ++j) {
        const int col = tileN + wn * 64 + j * 16 + l15;
        const float bv = bias[col];
#pragma unroll
        for (int i = 0; i < 8; ++i) {
            const int row0 = tileM + wm * 128 + i * 16 + (qf << 2);
#pragma unroll
            for (int rr = 0; rr < 4; ++rr) {
                C[(size_t)(row0 + rr) * N_DIM + col] = acc[i][j][rr] + bv;
            }
        }
    }

#undef STAGE_A
#undef STAGE_B
#undef READ_A
#undef READ_B
#undef MFMA16
#undef PHASE
#undef KTILE
}

// ---------------------------------------------------------------------------
extern "C" void kernel_launch(void* const* d_in, const int* in_sizes, int n_in,
                              void* d_out, int out_size, void* d_ws, size_t ws_size,
                              hipStream_t stream) {
    const float* x    = (const float*)d_in[0];  // [M,K]
    const float* w    = (const float*)d_in[1];  // [N,K]
    const float* bias = (const float*)d_in[2];  // [N]
    float* out        = (float*)d_out;          // [M,N]

    const int nElem = M_DIM * K_DIM;
    bf16* xb = (bf16*)d_ws;
    bf16* wb = xb + (size_t)nElem;

    prep_kernel<<<nElem / 4 / 256, 256, 0, stream>>>(x, w, xb, wb);

    dim3 grid(N_DIM / BN, M_DIM / BM);          // 16 x 16 = 256 blocks = 1/CU
    gemm_bin_kernel<<<grid, 512, 0, stream>>>(xb, wb, bias, out);
}